// Round 1
// baseline (24487.778 us; speedup 1.0000x reference)
//
#include <hip/hip_runtime.h>
#include <hip/hip_bf16.h>
#include <stdint.h>

// LSTM, persistent-kernel design:
//   grid = 256 WGs (1/CU, all co-resident), block = 256 threads = 4 waves.
//   WG (rb,cb): rows rb*32..+32 (rb<8), h-cols cb*32..+32 (cb<32).
//   Wave w = gate w (i,f,g,o). B-frags (weights, bf16) live in VGPRs/LDS.
//   Per step: gates = [x_t | h_t] @ [Wi;Wh] via mfma_f32_16x16x32_bf16,
//   LDS exchange of gate pre-acts, c update in thread-private fp32 regs,
//   h -> bf16 ping-pong buffer in ws, software inter-step barrier.

typedef __bf16 bf16x8 __attribute__((ext_vector_type(8)));
typedef float  f32x4  __attribute__((ext_vector_type(4)));

union U8 { bf16x8 v; __bf16 e[8]; };

#define MFMA16(a,b,c) __builtin_amdgcn_mfma_f32_16x16x32_bf16((a),(b),(c),0,0,0)

__global__ __launch_bounds__(256, 1) void lstm_persist(
    const float* __restrict__ x,
    const float* __restrict__ Wii, const float* __restrict__ Whi, const float* __restrict__ bi,
    const float* __restrict__ Wif, const float* __restrict__ Whf, const float* __restrict__ bfv,
    const float* __restrict__ Wig, const float* __restrict__ Whg, const float* __restrict__ bgv,
    const float* __restrict__ Wio, const float* __restrict__ Who, const float* __restrict__ bov,
    float* __restrict__ out,
    __bf16* __restrict__ hbuf,   // ws: 2 * 256*1024 bf16 ping-pong
    uint32_t* cnt)               // ws: barrier counter (monotone)
{
  constexpr int S = 512;
  // LDS: x-weight slab (first 128 k of Wi, 128 gate-cols, padded stride 136),
  //      gate-preact exchange buffer, h-store transpose buffer.  ~53.8 KB.
  __shared__ __align__(16) __bf16 xBl[128 * 136];
  __shared__ __align__(16) float  Pbuf[4096];
  __shared__ __align__(16) __bf16 transb[32 * 40];

  const int wg   = blockIdx.x;
  const int rb   = wg >> 5;     // 8 row blocks of 32 rows
  const int cb   = wg & 31;     // 32 col blocks of 32 h-cols
  const int tid  = threadIdx.x;
  const int wv   = tid >> 6;    // wave id == gate id
  const int lane = tid & 63;
  const int l15  = lane & 15;
  const int quad = lane >> 4;

  const float* Wi_g = (wv & 2) ? ((wv & 1) ? Wio : Wig) : ((wv & 1) ? Wif : Wii);
  const float* Wh_g = (wv & 2) ? ((wv & 1) ? Who : Whg) : ((wv & 1) ? Whf : Whi);

  // ---- one-time: preload B fragments (weights) into registers, bf16 ----
  // B-frag layout (verified m89/m120 family): lane holds B[k][n] with
  // n = lane&15, k = quad*8 + j (j = vector element).
  bf16x8 hB[32][2];   // Wh k-tiles 0..31  (k = 0..1023 of h-part)
  bf16x8 xB[12][2];   // Wi k-tiles 4..15  (k = 128..511 of x-part)
  #pragma unroll
  for (int nt = 0; nt < 2; ++nt) {
    const int col = cb * 32 + nt * 16 + l15;
    #pragma unroll
    for (int kt = 0; kt < 32; ++kt) {
      U8 u;
      #pragma unroll
      for (int j = 0; j < 8; ++j)
        u.e[j] = (__bf16)Wh_g[(kt * 32 + quad * 8 + j) * 1024 + col];
      hB[kt][nt] = u.v;
    }
    #pragma unroll
    for (int kt = 0; kt < 12; ++kt) {
      U8 u;
      #pragma unroll
      for (int j = 0; j < 8; ++j)
        u.e[j] = (__bf16)Wi_g[((kt + 4) * 32 + quad * 8 + j) * 1024 + col];
      xB[kt][nt] = u.v;
    }
  }
  // ---- one-time: stage Wi k=0..127 (all 4 gates, this cb) into LDS ----
  {
    const int gc  = tid >> 1;          // 0..127 gate-col
    const int g2  = gc >> 5;
    const float* W = (g2 & 2) ? ((g2 & 1) ? Wio : Wig) : ((g2 & 1) ? Wif : Wii);
    const int col = cb * 32 + (gc & 31);
    const int k0  = (tid & 1) * 64;
    for (int kk = 0; kk < 64; ++kk)
      xBl[gc * 136 + k0 + kk] = (__bf16)W[(k0 + kk) * 1024 + col];
  }

  // ---- reducer-role constants (independent of gate role) ----
  const int nt_r   = (tid >> 6) & 1;
  const int mt_r   = (tid >> 7) & 1;
  const int col_l  = nt_r * 16 + l15;           // 0..31 local h-col
  const int row0_l = mt_r * 16 + quad * 4;      // 0..28 local row (4 rows)
  const int gcol   = cb * 32 + col_l;
  const int grow0  = rb * 32 + row0_l;
  const float bias_i = bi[gcol], bias_f = bfv[gcol], bias_g = bgv[gcol], bias_o = bov[gcol];

  f32x4 ccell = {0.f, 0.f, 0.f, 0.f};          // persistent cell state (fp32)

  __bf16* hb0 = hbuf;
  __bf16* hb1 = hbuf + 262144;

  // A-operand bases. A-frag (verified): lane holds A[m][k], m = lane&15,
  // k = quad*8 + j. Rows are this WG's rows; k<512 from x (fp32), rest from h.
  const float* xr0 = x + (size_t)(rb * 32 +  0 + l15) * (512 * 512) + quad * 8;
  const float* xr1 = x + (size_t)(rb * 32 + 16 + l15) * (512 * 512) + quad * 8;
  const int hrow0 = (rb * 32 +  0 + l15) * 1024 + quad * 8;
  const int hrow1 = (rb * 32 + 16 + l15) * 1024 + quad * 8;
  const __bf16* xbl0 = &xBl[(wv * 32 +  0 + l15) * 136 + quad * 8];
  const __bf16* xbl1 = &xBl[(wv * 32 + 16 + l15) * 136 + quad * 8];

  __syncthreads();  // xBl ready

  for (int t = 0; t < S; ++t) {
    f32x4 a00 = {0,0,0,0}, a01 = {0,0,0,0}, a10 = {0,0,0,0}, a11 = {0,0,0,0};

    // ---- x-phase: issued BEFORE the barrier wait (hides barrier latency) ----
    const float* p0 = xr0 + t * 512;
    const float* p1 = xr1 + t * 512;
    #pragma unroll
    for (int kt = 0; kt < 16; ++kt) {
      const float4 u0 = *(const float4*)(p0 + kt * 32);
      const float4 u1 = *(const float4*)(p0 + kt * 32 + 4);
      const float4 v0 = *(const float4*)(p1 + kt * 32);
      const float4 v1 = *(const float4*)(p1 + kt * 32 + 4);
      U8 A0, A1;
      A0.e[0]=(__bf16)u0.x; A0.e[1]=(__bf16)u0.y; A0.e[2]=(__bf16)u0.z; A0.e[3]=(__bf16)u0.w;
      A0.e[4]=(__bf16)u1.x; A0.e[5]=(__bf16)u1.y; A0.e[6]=(__bf16)u1.z; A0.e[7]=(__bf16)u1.w;
      A1.e[0]=(__bf16)v0.x; A1.e[1]=(__bf16)v0.y; A1.e[2]=(__bf16)v0.z; A1.e[3]=(__bf16)v0.w;
      A1.e[4]=(__bf16)v1.x; A1.e[5]=(__bf16)v1.y; A1.e[6]=(__bf16)v1.z; A1.e[7]=(__bf16)v1.w;
      bf16x8 b0, b1;
      if (kt < 4) { b0 = *(const bf16x8*)(xbl0 + kt * 32); b1 = *(const bf16x8*)(xbl1 + kt * 32); }
      else        { b0 = xB[kt - 4][0];                    b1 = xB[kt - 4][1]; }
      a00 = MFMA16(A0.v, b0, a00);  a01 = MFMA16(A0.v, b1, a01);
      a10 = MFMA16(A1.v, b0, a10);  a11 = MFMA16(A1.v, b1, a11);
    }

    // ---- inter-step barrier: wait for all h(t) stores of step t-1 ----
    if (tid == 0) {
      const uint32_t target = (uint32_t)t * 256u;
      while (__hip_atomic_load(cnt, __ATOMIC_RELAXED, __HIP_MEMORY_SCOPE_AGENT) < target)
        __builtin_amdgcn_s_sleep(2);
    }
    __syncthreads();
    __builtin_amdgcn_fence(__ATOMIC_ACQUIRE, "agent");

    // ---- h-phase ----
    const __bf16* hcur = (t & 1) ? hb1 : hb0;
    const __bf16* h0p = hcur + hrow0;
    const __bf16* h1p = hcur + hrow1;
    #pragma unroll
    for (int kt = 0; kt < 32; ++kt) {
      const bf16x8 A0 = *(const bf16x8*)(h0p + kt * 32);
      const bf16x8 A1 = *(const bf16x8*)(h1p + kt * 32);
      a00 = MFMA16(A0, hB[kt][0], a00);  a01 = MFMA16(A0, hB[kt][1], a01);
      a10 = MFMA16(A1, hB[kt][0], a10);  a11 = MFMA16(A1, hB[kt][1], a11);
    }

    // ---- exchange gate pre-acts through LDS ----
    // C/D layout (verified m89/m91): col = lane&15, row = quad*4 + reg.
    *(f32x4*)&Pbuf[((wv * 4 + 0) * 64 + lane) * 4] = a00;  // (mt0,nt0)
    *(f32x4*)&Pbuf[((wv * 4 + 1) * 64 + lane) * 4] = a01;  // (mt0,nt1)
    *(f32x4*)&Pbuf[((wv * 4 + 2) * 64 + lane) * 4] = a10;  // (mt1,nt0)
    *(f32x4*)&Pbuf[((wv * 4 + 3) * 64 + lane) * 4] = a11;  // (mt1,nt1)
    __syncthreads();

    const int sr = ((mt_r * 2 + nt_r) * 64 + lane) * 4;
    const f32x4 pi = *(const f32x4*)&Pbuf[0 * 1024 + sr];
    const f32x4 pf = *(const f32x4*)&Pbuf[1 * 1024 + sr];
    const f32x4 pg = *(const f32x4*)&Pbuf[2 * 1024 + sr];
    const f32x4 po = *(const f32x4*)&Pbuf[3 * 1024 + sr];

    float hn[4];
    #pragma unroll
    for (int r = 0; r < 4; ++r) {
      const float gi = __builtin_amdgcn_rcpf(1.f + __expf(-(pi[r] + bias_i)));
      const float gf = __builtin_amdgcn_rcpf(1.f + __expf(-(pf[r] + bias_f)));
      const float gg = 2.f * __builtin_amdgcn_rcpf(1.f + __expf(-2.f * (pg[r] + bias_g))) - 1.f;
      const float go = __builtin_amdgcn_rcpf(1.f + __expf(-(po[r] + bias_o)));
      const float cn = gi * gg + gf * ccell[r];
      ccell[r] = cn;
      const float tc = 2.f * __builtin_amdgcn_rcpf(1.f + __expf(-2.f * cn)) - 1.f;
      hn[r] = go * tc;
      transb[(row0_l + r) * 40 + col_l] = (__bf16)hn[r];
    }
    __syncthreads();

    // ---- coalesced h store to ping-pong buffer ----
    __bf16* hnxt = (t & 1) ? hb0 : hb1;
    if (tid < 128) {
      const int rl = tid >> 2, ch = tid & 3;
      const bf16x8 v = *(const bf16x8*)&transb[rl * 40 + ch * 8];
      *(bf16x8*)(hnxt + (rb * 32 + rl) * 1024 + cb * 32 + ch * 8) = v;
    }
    if (t == S - 1) {
      #pragma unroll
      for (int r = 0; r < 4; ++r) {
        out[(grow0 + r) * 1024 + gcol]          = hn[r];        // h_T
        out[262144 + (grow0 + r) * 1024 + gcol] = ccell[r];     // c_T
      }
    }
    __builtin_amdgcn_fence(__ATOMIC_RELEASE, "agent");
    __syncthreads();
    if (tid == 0)
      __hip_atomic_fetch_add(cnt, 1u, __ATOMIC_RELEASE, __HIP_MEMORY_SCOPE_AGENT);
  }
}

extern "C" void kernel_launch(void* const* d_in, const int* in_sizes, int n_in,
                              void* d_out, int out_size, void* d_ws, size_t ws_size,
                              hipStream_t stream) {
  const float* xp  = (const float*)d_in[0];
  const float* Wii = (const float*)d_in[1];
  const float* Whi = (const float*)d_in[2];
  const float* bi  = (const float*)d_in[3];
  const float* Wif = (const float*)d_in[4];
  const float* Whf = (const float*)d_in[5];
  const float* bf_ = (const float*)d_in[6];
  const float* Wig = (const float*)d_in[7];
  const float* Whg = (const float*)d_in[8];
  const float* bg  = (const float*)d_in[9];
  const float* Wio = (const float*)d_in[10];
  const float* Who = (const float*)d_in[11];
  const float* bo  = (const float*)d_in[12];
  float* out = (float*)d_out;

  __bf16*   hbuf = (__bf16*)d_ws;
  uint32_t* cnt  = (uint32_t*)((char*)d_ws + 2u * 262144u * sizeof(__bf16));

  // zero h0 ping-pong + barrier counter (ws is re-poisoned before every launch)
  hipMemsetAsync(d_ws, 0, 2u * 262144u * sizeof(__bf16) + 64u, stream);

  lstm_persist<<<dim3(256), dim3(256), 0, stream>>>(
      xp, Wii, Whi, bi, Wif, Whf, bf_, Wig, Whg, bg, Wio, Who, bo,
      out, hbuf, cnt);
}

// Round 2
// 6262.369 us; speedup vs baseline: 3.9103x; 3.9103x over previous
//
#include <hip/hip_runtime.h>
#include <hip/hip_bf16.h>
#include <stdint.h>

// LSTM persistent kernel, round 2.
//   grid = 256 WGs (1/CU), block = 512 threads = 8 waves.
//   WG (rb,cb): rows rb*32..+32 (rb<8), h-cols cb*32..+32 (cb<32).
//   Wave wv: gate g = wv&3, k-half hf = wv>>2. Each wave owns weight frags:
//     hB: Wh[g][hf*512 .. hf*512+512) x 32 cols  (128 VGPRs)
//     xB: Wi[g][hf*256 .. hf*256+256) x 32 cols  ( 64 VGPRs)
//   Cross-XCD h exchange via sc0/sc1 (device-coherent) loads/stores ONLY —
//   no agent fences (round-1 fences emitted buffer_inv/buffer_wbl2 per step,
//   nuking L2 and causing 2.1 GB x re-fetch + 47us/step).
//   Ordering: sc1 stores -> s_waitcnt vmcnt(0) -> __syncthreads -> relaxed
//   agent fetch_add; readers spin on relaxed agent load then sc1-load h.

typedef __bf16 bf16x8 __attribute__((ext_vector_type(8)));
typedef float  f32x4  __attribute__((ext_vector_type(4)));
typedef float  f32x2  __attribute__((ext_vector_type(2)));
typedef uint32_t u32x4 __attribute__((ext_vector_type(4)));

union U8 { bf16x8 v; __bf16 e[8]; };
union PK { uint32_t u; __bf16 e[2]; };

#define MFMA16(a,b,c) __builtin_amdgcn_mfma_f32_16x16x32_bf16((a),(b),(c),0,0,0)

// device-coherent 16B load: bypass L1/L2, read from coherence point
#define GLOADX4(dst, base, OFF)                                              \
  asm volatile("global_load_dwordx4 %0, %1, off offset:" #OFF " sc0 sc1"     \
               : "=v"(dst) : "v"(base))
// device-coherent 4B store: write through to coherence point
#define GSTORE1(base, val)                                                   \
  asm volatile("global_store_dword %0, %1, off sc0 sc1"                      \
               :: "v"(base), "v"(val) : "memory")
#define WAIT_VM0() asm volatile("s_waitcnt vmcnt(0)" ::: "memory")

__global__ __launch_bounds__(512, 2) void lstm_persist(
    const float* __restrict__ x,
    const float* __restrict__ Wii, const float* __restrict__ Whi, const float* __restrict__ bi,
    const float* __restrict__ Wif, const float* __restrict__ Whf, const float* __restrict__ bfv,
    const float* __restrict__ Wig, const float* __restrict__ Whg, const float* __restrict__ bgv,
    const float* __restrict__ Wio, const float* __restrict__ Who, const float* __restrict__ bov,
    float* __restrict__ out,
    uint32_t* __restrict__ hbuf,   // ws: 2 * 256*1024 bf16 ping-pong (as dwords)
    uint32_t* cnt)                 // ws: barrier counter (monotone)
{
  constexpr int S = 512;
  // LDS: h slab (32 rows x 1024 bf16, row stride 516 dwords = +16 bf16 pad),
  //      gate/half pre-act exchange, h-store transpose.  ~98.6 KB.
  __shared__ uint32_t hsu[32 * 516];
  __shared__ float    Pbuf[8192];
  __shared__ __bf16   transb[32 * 33];

  const int wg   = blockIdx.x;
  const int rb   = wg >> 5;      // 8 row blocks of 32 rows
  const int cb   = wg & 31;      // 32 col blocks of 32 h-cols
  const int tid  = threadIdx.x;
  const int wv   = tid >> 6;     // 8 waves
  const int g    = wv & 3;       // gate
  const int hf   = wv >> 2;      // k-half
  const int lane = tid & 63;
  const int l15  = lane & 15;
  const int quad = lane >> 4;

  const float* Wi_g = (g == 0) ? Wii : (g == 1) ? Wif : (g == 2) ? Wig : Wio;
  const float* Wh_g = (g == 0) ? Whi : (g == 1) ? Whf : (g == 2) ? Whg : Who;

  // ---- one-time: weight B-fragments into registers (bf16) ----
  // B-frag layout: lane holds B[k][n], n = lane&15, k = quad*8 + j.
  bf16x8 hB[16][2];   // Wh k-tiles for this half (k = hf*512 .. +512)
  bf16x8 xB[8][2];    // Wi k-tiles for this half (k = hf*256 .. +256)
  #pragma unroll
  for (int nt = 0; nt < 2; ++nt) {
    const int col = cb * 32 + nt * 16 + l15;
    #pragma unroll
    for (int kt = 0; kt < 16; ++kt) {
      U8 u;
      #pragma unroll
      for (int j = 0; j < 8; ++j)
        u.e[j] = (__bf16)Wh_g[(size_t)(hf * 512 + kt * 32 + quad * 8 + j) * 1024 + col];
      hB[kt][nt] = u.v;
    }
    #pragma unroll
    for (int kt = 0; kt < 8; ++kt) {
      U8 u;
      #pragma unroll
      for (int j = 0; j < 8; ++j)
        u.e[j] = (__bf16)Wi_g[(size_t)(hf * 256 + kt * 32 + quad * 8 + j) * 1024 + col];
      xB[kt][nt] = u.v;
    }
  }

  // ---- reducer-role constants (512 threads; 2 cells each) ----
  const int acc_r  = (tid >> 7) & 3;           // which accumulator (mt*2+nt)
  const int rp_r   = (tid >> 6) & 1;           // reg pair within acc
  const int mt_r   = acc_r >> 1, nt_r = acc_r & 1;
  const int col_l  = nt_r * 16 + l15;          // 0..31 local col
  const int row0_l = mt_r * 16 + quad * 4 + rp_r * 2;  // local row of cell 0
  const int gcol   = cb * 32 + col_l;
  const int grow0  = rb * 32 + row0_l;
  const float bias_i = bi[gcol], bias_f = bfv[gcol];
  const float bias_g = bgv[gcol], bias_o = bov[gcol];
  float cc0 = 0.f, cc1 = 0.f;                  // persistent cell state

  uint32_t* const hb0 = hbuf;                  // dword pointers (512 KB each)
  uint32_t* const hb1 = hbuf + 131072;

  // A-operand bases: x rows for this WG (m = l15 / l15+16), k-half offset
  const float* xr0 = x + (size_t)(rb * 32 + l15) * (512 * 512) + hf * 256 + quad * 8;
  const float* xr1 = xr0 + (size_t)16 * (512 * 512);

  // cooperative h-slab load role: row = tid>>4 (32 rows), seg = tid&15
  const int crow = tid >> 4, cseg = tid & 15;
  uint32_t* const ldst = hsu + crow * 516 + cseg * 4;
  const size_t gofs = (size_t)(rb * 32 + crow) * 512 + cseg * 4;

  // h-phase LDS A-frag bases
  const uint32_t* hA0 = hsu + l15 * 516 + hf * 256 + quad * 4;
  const uint32_t* hA1 = hsu + (l15 + 16) * 516 + hf * 256 + quad * 4;

  // h-store role
  const int srow = tid >> 4, scol = (tid & 15) * 2;
  const size_t sdst = (size_t)(rb * 32 + srow) * 512 + cb * 16 + (tid & 15);

  for (int t = 0; t < S; ++t) {
    f32x4 a00 = {0,0,0,0}, a01 = {0,0,0,0}, a10 = {0,0,0,0}, a11 = {0,0,0,0};

    // ---- x-phase (independent of barrier; hides spin latency) ----
    const float* p0 = xr0 + (size_t)t * 512;
    const float* p1 = xr1 + (size_t)t * 512;
    #pragma unroll
    for (int kt = 0; kt < 8; ++kt) {
      const float4 u0 = *(const float4*)(p0 + kt * 32);
      const float4 u1 = *(const float4*)(p0 + kt * 32 + 4);
      const float4 v0 = *(const float4*)(p1 + kt * 32);
      const float4 v1 = *(const float4*)(p1 + kt * 32 + 4);
      U8 A0, A1;
      A0.e[0]=(__bf16)u0.x; A0.e[1]=(__bf16)u0.y; A0.e[2]=(__bf16)u0.z; A0.e[3]=(__bf16)u0.w;
      A0.e[4]=(__bf16)u1.x; A0.e[5]=(__bf16)u1.y; A0.e[6]=(__bf16)u1.z; A0.e[7]=(__bf16)u1.w;
      A1.e[0]=(__bf16)v0.x; A1.e[1]=(__bf16)v0.y; A1.e[2]=(__bf16)v0.z; A1.e[3]=(__bf16)v0.w;
      A1.e[4]=(__bf16)v1.x; A1.e[5]=(__bf16)v1.y; A1.e[6]=(__bf16)v1.z; A1.e[7]=(__bf16)v1.w;
      a00 = MFMA16(A0.v, xB[kt][0], a00);  a01 = MFMA16(A0.v, xB[kt][1], a01);
      a10 = MFMA16(A1.v, xB[kt][0], a10);  a11 = MFMA16(A1.v, xB[kt][1], a11);
    }

    // ---- inter-step barrier (no fences; counter is device-scope atomic) ----
    if (tid == 0) {
      const uint32_t target = (uint32_t)t * 256u;
      while (__hip_atomic_load(cnt, __ATOMIC_RELAXED, __HIP_MEMORY_SCOPE_AGENT) < target)
        __builtin_amdgcn_s_sleep(2);
    }
    __syncthreads();

    // ---- cooperative device-coherent load of h slab into LDS ----
    {
      const uint32_t* hcur = ((t & 1) ? hb1 : hb0) + gofs;
      u32x4 tv0, tv1, tv2, tv3, tv4, tv5, tv6, tv7;
      GLOADX4(tv0, hcur, 0);    GLOADX4(tv1, hcur, 256);
      GLOADX4(tv2, hcur, 512);  GLOADX4(tv3, hcur, 768);
      GLOADX4(tv4, hcur, 1024); GLOADX4(tv5, hcur, 1280);
      GLOADX4(tv6, hcur, 1536); GLOADX4(tv7, hcur, 1792);
      WAIT_VM0();
      *(u32x4*)(ldst +   0) = tv0;  *(u32x4*)(ldst +  64) = tv1;
      *(u32x4*)(ldst + 128) = tv2;  *(u32x4*)(ldst + 192) = tv3;
      *(u32x4*)(ldst + 256) = tv4;  *(u32x4*)(ldst + 320) = tv5;
      *(u32x4*)(ldst + 384) = tv6;  *(u32x4*)(ldst + 448) = tv7;
    }
    __syncthreads();

    // ---- h-phase: 16 k-tiles from LDS ----
    #pragma unroll
    for (int kt = 0; kt < 16; ++kt) {
      const bf16x8 A0 = *(const bf16x8*)(hA0 + kt * 16);
      const bf16x8 A1 = *(const bf16x8*)(hA1 + kt * 16);
      a00 = MFMA16(A0, hB[kt][0], a00);  a01 = MFMA16(A0, hB[kt][1], a01);
      a10 = MFMA16(A1, hB[kt][0], a10);  a11 = MFMA16(A1, hB[kt][1], a11);
    }

    // ---- exchange pre-acts: slot = wv (= hf*4+g), acc = mt*2+nt ----
    // C/D layout: col = lane&15 (+nt*16), row = quad*4 + reg (+mt*16).
    *(f32x4*)&Pbuf[(wv * 4 + 0) * 256 + lane * 4] = a00;
    *(f32x4*)&Pbuf[(wv * 4 + 1) * 256 + lane * 4] = a01;
    *(f32x4*)&Pbuf[(wv * 4 + 2) * 256 + lane * 4] = a10;
    *(f32x4*)&Pbuf[(wv * 4 + 3) * 256 + lane * 4] = a11;
    __syncthreads();

    // ---- reduce halves, activations, cell update (2 cells/thread) ----
    const int off = acc_r * 256 + lane * 4 + rp_r * 2;
    const f32x2 qi = *(const f32x2*)&Pbuf[0 * 1024 + off] ;
    const f32x2 ri = *(const f32x2*)&Pbuf[4 * 1024 + off];
    const f32x2 qf = *(const f32x2*)&Pbuf[1 * 1024 + off];
    const f32x2 rf = *(const f32x2*)&Pbuf[5 * 1024 + off];
    const f32x2 qg = *(const f32x2*)&Pbuf[2 * 1024 + off];
    const f32x2 rg = *(const f32x2*)&Pbuf[6 * 1024 + off];
    const f32x2 qo = *(const f32x2*)&Pbuf[3 * 1024 + off];
    const f32x2 ro = *(const f32x2*)&Pbuf[7 * 1024 + off];

    float hn0, hn1;
    {
      const float pi0 = qi[0] + ri[0] + bias_i, pi1 = qi[1] + ri[1] + bias_i;
      const float pf0 = qf[0] + rf[0] + bias_f, pf1 = qf[1] + rf[1] + bias_f;
      const float pg0 = qg[0] + rg[0] + bias_g, pg1 = qg[1] + rg[1] + bias_g;
      const float po0 = qo[0] + ro[0] + bias_o, po1 = qo[1] + ro[1] + bias_o;
      const float gi0 = __builtin_amdgcn_rcpf(1.f + __expf(-pi0));
      const float gi1 = __builtin_amdgcn_rcpf(1.f + __expf(-pi1));
      const float gf0 = __builtin_amdgcn_rcpf(1.f + __expf(-pf0));
      const float gf1 = __builtin_amdgcn_rcpf(1.f + __expf(-pf1));
      const float gg0 = 2.f * __builtin_amdgcn_rcpf(1.f + __expf(-2.f * pg0)) - 1.f;
      const float gg1 = 2.f * __builtin_amdgcn_rcpf(1.f + __expf(-2.f * pg1)) - 1.f;
      const float go0 = __builtin_amdgcn_rcpf(1.f + __expf(-po0));
      const float go1 = __builtin_amdgcn_rcpf(1.f + __expf(-po1));
      cc0 = gi0 * gg0 + gf0 * cc0;
      cc1 = gi1 * gg1 + gf1 * cc1;
      const float tc0 = 2.f * __builtin_amdgcn_rcpf(1.f + __expf(-2.f * cc0)) - 1.f;
      const float tc1 = 2.f * __builtin_amdgcn_rcpf(1.f + __expf(-2.f * cc1)) - 1.f;
      hn0 = go0 * tc0;
      hn1 = go1 * tc1;
      transb[(row0_l + 0) * 33 + col_l] = (__bf16)hn0;
      transb[(row0_l + 1) * 33 + col_l] = (__bf16)hn1;
    }
    __syncthreads();

    // ---- coalesced device-coherent h store (1 dword / thread) ----
    {
      PK pk;
      pk.e[0] = transb[srow * 33 + scol];
      pk.e[1] = transb[srow * 33 + scol + 1];
      uint32_t* dst = ((t & 1) ? hb0 : hb1) + sdst;
      GSTORE1(dst, pk.u);
    }
    if (t == S - 1) {
      out[(size_t)(grow0 + 0) * 1024 + gcol] = hn0;              // h_T
      out[(size_t)(grow0 + 1) * 1024 + gcol] = hn1;
      out[262144 + (size_t)(grow0 + 0) * 1024 + gcol] = cc0;     // c_T
      out[262144 + (size_t)(grow0 + 1) * 1024 + gcol] = cc1;
    }
    WAIT_VM0();            // h stores are at the coherence point
    __syncthreads();       // all threads of this WG drained
    if (tid == 0)
      __hip_atomic_fetch_add(cnt, 1u, __ATOMIC_RELAXED, __HIP_MEMORY_SCOPE_AGENT);
  }
}

extern "C" void kernel_launch(void* const* d_in, const int* in_sizes, int n_in,
                              void* d_out, int out_size, void* d_ws, size_t ws_size,
                              hipStream_t stream) {
  const float* xp  = (const float*)d_in[0];
  const float* Wii = (const float*)d_in[1];
  const float* Whi = (const float*)d_in[2];
  const float* bi  = (const float*)d_in[3];
  const float* Wif = (const float*)d_in[4];
  const float* Whf = (const float*)d_in[5];
  const float* bf_ = (const float*)d_in[6];
  const float* Wig = (const float*)d_in[7];
  const float* Whg = (const float*)d_in[8];
  const float* bg  = (const float*)d_in[9];
  const float* Wio = (const float*)d_in[10];
  const float* Who = (const float*)d_in[11];
  const float* bo  = (const float*)d_in[12];
  float* out = (float*)d_out;

  uint32_t* hbuf = (uint32_t*)d_ws;
  uint32_t* cnt  = (uint32_t*)((char*)d_ws + 2u * 262144u * sizeof(__bf16));

  // zero h ping-pong + barrier counter (ws is re-poisoned before every launch)
  hipMemsetAsync(d_ws, 0, 2u * 262144u * sizeof(__bf16) + 64u, stream);

  lstm_persist<<<dim3(256), dim3(512), 0, stream>>>(
      xp, Wii, Whi, bi, Wif, Whf, bf_, Wig, Whg, bg, Wio, Who, bo,
      out, hbuf, cnt);
}

// Round 3
// 6031.042 us; speedup vs baseline: 4.0603x; 1.0384x over previous
//
#include <hip/hip_runtime.h>
#include <hip/hip_bf16.h>
#include <stdint.h>

// LSTM persistent kernel, round 3.
//   grid = 256 WGs (1/CU), block = 512 threads = 8 waves.
//   WG (rb,cb): rows rb*32..+32 (rb<8), h-cols cb*32..+32 (cb<32).
//   Wave wv: gate g = wv&3, k-half hf = wv>>2; weight B-frags in VGPRs/AGPRs.
//   Round-3 change: the inter-step barrier is PER ROW-GROUP (8 independent
//   counters, 32 arrivals each, 1 KB apart) instead of one global counter
//   with 256 arrivals + 256 spinning CUs on one line (round-2's 12us/step
//   was dominated by that single-line atomic/spin contention). Row groups
//   are independent (LSTM batch rows don't interact), so this is exact.

typedef __bf16 bf16x8 __attribute__((ext_vector_type(8)));
typedef float  f32x4  __attribute__((ext_vector_type(4)));
typedef float  f32x2  __attribute__((ext_vector_type(2)));
typedef uint32_t u32x4 __attribute__((ext_vector_type(4)));

union U8 { bf16x8 v; __bf16 e[8]; };
union PK { uint32_t u; __bf16 e[2]; };

#define MFMA16(a,b,c) __builtin_amdgcn_mfma_f32_16x16x32_bf16((a),(b),(c),0,0,0)

// device-coherent 16B load: bypass L1/L2, read from coherence point (L3)
#define GLOADX4(dst, base, OFF)                                              \
  asm volatile("global_load_dwordx4 %0, %1, off offset:" #OFF " sc0 sc1"     \
               : "=v"(dst) : "v"(base))
// device-coherent 4B store: write through to coherence point
#define GSTORE1(base, val)                                                   \
  asm volatile("global_store_dword %0, %1, off sc0 sc1"                      \
               :: "v"(base), "v"(val) : "memory")
#define WAIT_VM0() asm volatile("s_waitcnt vmcnt(0)" ::: "memory")

__global__ __launch_bounds__(512, 2) void lstm_persist(
    const float* __restrict__ x,
    const float* __restrict__ Wii, const float* __restrict__ Whi, const float* __restrict__ bi,
    const float* __restrict__ Wif, const float* __restrict__ Whf, const float* __restrict__ bfv,
    const float* __restrict__ Wig, const float* __restrict__ Whg, const float* __restrict__ bgv,
    const float* __restrict__ Wio, const float* __restrict__ Who, const float* __restrict__ bov,
    float* __restrict__ out,
    uint32_t* __restrict__ hbuf,   // ws: 2 * 256*1024 bf16 ping-pong (as dwords)
    uint32_t* cnts)                // ws: 8 per-row-group counters, 256 dwords apart
{
  constexpr int S = 512;
  // LDS: h slab (32 rows x 1024 bf16, row stride 516 dwords = +16 bf16 pad),
  //      gate/half pre-act exchange, h-store transpose.  ~100.6 KB.
  __shared__ uint32_t hsu[32 * 516];
  __shared__ float    Pbuf[8192];
  __shared__ __bf16   transb[32 * 33];

  const int wg   = blockIdx.x;
  const int rb   = wg >> 5;      // 8 row blocks of 32 rows
  const int cb   = wg & 31;      // 32 col blocks of 32 h-cols
  const int tid  = threadIdx.x;
  const int wv   = tid >> 6;     // 8 waves
  const int g    = wv & 3;       // gate
  const int hf   = wv >> 2;      // k-half
  const int lane = tid & 63;
  const int l15  = lane & 15;
  const int quad = lane >> 4;

  uint32_t* const mycnt = cnts + rb * 256;   // 1 KB line spacing per group

  const float* Wi_g = (g == 0) ? Wii : (g == 1) ? Wif : (g == 2) ? Wig : Wio;
  const float* Wh_g = (g == 0) ? Whi : (g == 1) ? Whf : (g == 2) ? Whg : Who;

  // ---- one-time: weight B-fragments into registers (bf16) ----
  // B-frag layout: lane holds B[k][n], n = lane&15, k = quad*8 + j.
  bf16x8 hB[16][2];   // Wh k-tiles for this half (k = hf*512 .. +512)
  bf16x8 xB[8][2];    // Wi k-tiles for this half (k = hf*256 .. +256)
  #pragma unroll
  for (int nt = 0; nt < 2; ++nt) {
    const int col = cb * 32 + nt * 16 + l15;
    #pragma unroll
    for (int kt = 0; kt < 16; ++kt) {
      U8 u;
      #pragma unroll
      for (int j = 0; j < 8; ++j)
        u.e[j] = (__bf16)Wh_g[(size_t)(hf * 512 + kt * 32 + quad * 8 + j) * 1024 + col];
      hB[kt][nt] = u.v;
    }
    #pragma unroll
    for (int kt = 0; kt < 8; ++kt) {
      U8 u;
      #pragma unroll
      for (int j = 0; j < 8; ++j)
        u.e[j] = (__bf16)Wi_g[(size_t)(hf * 256 + kt * 32 + quad * 8 + j) * 1024 + col];
      xB[kt][nt] = u.v;
    }
  }

  // ---- reducer-role constants (512 threads; 2 cells each) ----
  const int acc_r  = (tid >> 7) & 3;           // which accumulator (mt*2+nt)
  const int rp_r   = (tid >> 6) & 1;           // reg pair within acc
  const int mt_r   = acc_r >> 1, nt_r = acc_r & 1;
  const int col_l  = nt_r * 16 + l15;          // 0..31 local col
  const int row0_l = mt_r * 16 + quad * 4 + rp_r * 2;  // local row of cell 0
  const int gcol   = cb * 32 + col_l;
  const int grow0  = rb * 32 + row0_l;
  const float bias_i = bi[gcol], bias_f = bfv[gcol];
  const float bias_g = bgv[gcol], bias_o = bov[gcol];
  float cc0 = 0.f, cc1 = 0.f;                  // persistent cell state

  uint32_t* const hb0 = hbuf;                  // dword pointers (512 KB each)
  uint32_t* const hb1 = hbuf + 131072;

  // A-operand bases: x rows for this WG (m = l15 / l15+16), k-half offset
  const float* xr0 = x + (size_t)(rb * 32 + l15) * (512 * 512) + hf * 256 + quad * 8;
  const float* xr1 = xr0 + (size_t)16 * (512 * 512);

  // cooperative h-slab load role: row = tid>>4 (32 rows), seg = tid&15
  const int crow = tid >> 4, cseg = tid & 15;
  uint32_t* const ldst = hsu + crow * 516 + cseg * 4;
  const size_t gofs = (size_t)(rb * 32 + crow) * 512 + cseg * 4;

  // h-phase LDS A-frag bases
  const uint32_t* hA0 = hsu + l15 * 516 + hf * 256 + quad * 4;
  const uint32_t* hA1 = hsu + (l15 + 16) * 516 + hf * 256 + quad * 4;

  // h-store role
  const int srow = tid >> 4, scol = (tid & 15) * 2;
  const size_t sdst = (size_t)(rb * 32 + srow) * 512 + cb * 16 + (tid & 15);

  for (int t = 0; t < S; ++t) {
    f32x4 a00 = {0,0,0,0}, a01 = {0,0,0,0}, a10 = {0,0,0,0}, a11 = {0,0,0,0};

    // ---- x-phase (independent of barrier; hides spin latency) ----
    const float* p0 = xr0 + (size_t)t * 512;
    const float* p1 = xr1 + (size_t)t * 512;
    #pragma unroll
    for (int kt = 0; kt < 8; ++kt) {
      const float4 u0 = *(const float4*)(p0 + kt * 32);
      const float4 u1 = *(const float4*)(p0 + kt * 32 + 4);
      const float4 v0 = *(const float4*)(p1 + kt * 32);
      const float4 v1 = *(const float4*)(p1 + kt * 32 + 4);
      U8 A0, A1;
      A0.e[0]=(__bf16)u0.x; A0.e[1]=(__bf16)u0.y; A0.e[2]=(__bf16)u0.z; A0.e[3]=(__bf16)u0.w;
      A0.e[4]=(__bf16)u1.x; A0.e[5]=(__bf16)u1.y; A0.e[6]=(__bf16)u1.z; A0.e[7]=(__bf16)u1.w;
      A1.e[0]=(__bf16)v0.x; A1.e[1]=(__bf16)v0.y; A1.e[2]=(__bf16)v0.z; A1.e[3]=(__bf16)v0.w;
      A1.e[4]=(__bf16)v1.x; A1.e[5]=(__bf16)v1.y; A1.e[6]=(__bf16)v1.z; A1.e[7]=(__bf16)v1.w;
      a00 = MFMA16(A0.v, xB[kt][0], a00);  a01 = MFMA16(A0.v, xB[kt][1], a01);
      a10 = MFMA16(A1.v, xB[kt][0], a10);  a11 = MFMA16(A1.v, xB[kt][1], a11);
    }

    // ---- inter-step barrier: wait for the 32 WGs of THIS row group ----
    if (tid == 0) {
      const uint32_t target = (uint32_t)t * 32u;
      while (__hip_atomic_load(mycnt, __ATOMIC_RELAXED, __HIP_MEMORY_SCOPE_AGENT) < target)
        __builtin_amdgcn_s_sleep(1);
    }
    __syncthreads();

    // ---- cooperative device-coherent load of h slab into LDS ----
    {
      const uint32_t* hcur = ((t & 1) ? hb1 : hb0) + gofs;
      u32x4 tv0, tv1, tv2, tv3, tv4, tv5, tv6, tv7;
      GLOADX4(tv0, hcur, 0);    GLOADX4(tv1, hcur, 256);
      GLOADX4(tv2, hcur, 512);  GLOADX4(tv3, hcur, 768);
      GLOADX4(tv4, hcur, 1024); GLOADX4(tv5, hcur, 1280);
      GLOADX4(tv6, hcur, 1536); GLOADX4(tv7, hcur, 1792);
      WAIT_VM0();
      *(u32x4*)(ldst +   0) = tv0;  *(u32x4*)(ldst +  64) = tv1;
      *(u32x4*)(ldst + 128) = tv2;  *(u32x4*)(ldst + 192) = tv3;
      *(u32x4*)(ldst + 256) = tv4;  *(u32x4*)(ldst + 320) = tv5;
      *(u32x4*)(ldst + 384) = tv6;  *(u32x4*)(ldst + 448) = tv7;
    }
    __syncthreads();

    // ---- h-phase: 16 k-tiles from LDS ----
    #pragma unroll
    for (int kt = 0; kt < 16; ++kt) {
      const bf16x8 A0 = *(const bf16x8*)(hA0 + kt * 16);
      const bf16x8 A1 = *(const bf16x8*)(hA1 + kt * 16);
      a00 = MFMA16(A0, hB[kt][0], a00);  a01 = MFMA16(A0, hB[kt][1], a01);
      a10 = MFMA16(A1, hB[kt][0], a10);  a11 = MFMA16(A1, hB[kt][1], a11);
    }

    // ---- exchange pre-acts: slot = wv (= hf*4+g), acc = mt*2+nt ----
    // C/D layout: col = lane&15 (+nt*16), row = quad*4 + reg (+mt*16).
    *(f32x4*)&Pbuf[(wv * 4 + 0) * 256 + lane * 4] = a00;
    *(f32x4*)&Pbuf[(wv * 4 + 1) * 256 + lane * 4] = a01;
    *(f32x4*)&Pbuf[(wv * 4 + 2) * 256 + lane * 4] = a10;
    *(f32x4*)&Pbuf[(wv * 4 + 3) * 256 + lane * 4] = a11;
    __syncthreads();

    // ---- reduce halves, activations, cell update (2 cells/thread) ----
    const int off = acc_r * 256 + lane * 4 + rp_r * 2;
    const f32x2 qi = *(const f32x2*)&Pbuf[0 * 1024 + off];
    const f32x2 ri = *(const f32x2*)&Pbuf[4 * 1024 + off];
    const f32x2 qf = *(const f32x2*)&Pbuf[1 * 1024 + off];
    const f32x2 rf = *(const f32x2*)&Pbuf[5 * 1024 + off];
    const f32x2 qg = *(const f32x2*)&Pbuf[2 * 1024 + off];
    const f32x2 rg = *(const f32x2*)&Pbuf[6 * 1024 + off];
    const f32x2 qo = *(const f32x2*)&Pbuf[3 * 1024 + off];
    const f32x2 ro = *(const f32x2*)&Pbuf[7 * 1024 + off];

    float hn0, hn1;
    {
      const float pi0 = qi[0] + ri[0] + bias_i, pi1 = qi[1] + ri[1] + bias_i;
      const float pf0 = qf[0] + rf[0] + bias_f, pf1 = qf[1] + rf[1] + bias_f;
      const float pg0 = qg[0] + rg[0] + bias_g, pg1 = qg[1] + rg[1] + bias_g;
      const float po0 = qo[0] + ro[0] + bias_o, po1 = qo[1] + ro[1] + bias_o;
      const float gi0 = __builtin_amdgcn_rcpf(1.f + __expf(-pi0));
      const float gi1 = __builtin_amdgcn_rcpf(1.f + __expf(-pi1));
      const float gf0 = __builtin_amdgcn_rcpf(1.f + __expf(-pf0));
      const float gf1 = __builtin_amdgcn_rcpf(1.f + __expf(-pf1));
      const float gg0 = 2.f * __builtin_amdgcn_rcpf(1.f + __expf(-2.f * pg0)) - 1.f;
      const float gg1 = 2.f * __builtin_amdgcn_rcpf(1.f + __expf(-2.f * pg1)) - 1.f;
      const float go0 = __builtin_amdgcn_rcpf(1.f + __expf(-po0));
      const float go1 = __builtin_amdgcn_rcpf(1.f + __expf(-po1));
      cc0 = gi0 * gg0 + gf0 * cc0;
      cc1 = gi1 * gg1 + gf1 * cc1;
      const float tc0 = 2.f * __builtin_amdgcn_rcpf(1.f + __expf(-2.f * cc0)) - 1.f;
      const float tc1 = 2.f * __builtin_amdgcn_rcpf(1.f + __expf(-2.f * cc1)) - 1.f;
      hn0 = go0 * tc0;
      hn1 = go1 * tc1;
      transb[(row0_l + 0) * 33 + col_l] = (__bf16)hn0;
      transb[(row0_l + 1) * 33 + col_l] = (__bf16)hn1;
    }
    __syncthreads();

    // ---- coalesced device-coherent h store (1 dword / thread) ----
    {
      PK pk;
      pk.e[0] = transb[srow * 33 + scol];
      pk.e[1] = transb[srow * 33 + scol + 1];
      uint32_t* dst = ((t & 1) ? hb0 : hb1) + sdst;
      GSTORE1(dst, pk.u);
    }
    if (t == S - 1) {
      out[(size_t)(grow0 + 0) * 1024 + gcol] = hn0;              // h_T
      out[(size_t)(grow0 + 1) * 1024 + gcol] = hn1;
      out[262144 + (size_t)(grow0 + 0) * 1024 + gcol] = cc0;     // c_T
      out[262144 + (size_t)(grow0 + 1) * 1024 + gcol] = cc1;
    }
    WAIT_VM0();            // h stores are at the coherence point
    __syncthreads();       // all threads of this WG drained
    if (tid == 0)
      __hip_atomic_fetch_add(mycnt, 1u, __ATOMIC_RELAXED, __HIP_MEMORY_SCOPE_AGENT);
  }
}

extern "C" void kernel_launch(void* const* d_in, const int* in_sizes, int n_in,
                              void* d_out, int out_size, void* d_ws, size_t ws_size,
                              hipStream_t stream) {
  const float* xp  = (const float*)d_in[0];
  const float* Wii = (const float*)d_in[1];
  const float* Whi = (const float*)d_in[2];
  const float* bi  = (const float*)d_in[3];
  const float* Wif = (const float*)d_in[4];
  const float* Whf = (const float*)d_in[5];
  const float* bf_ = (const float*)d_in[6];
  const float* Wig = (const float*)d_in[7];
  const float* Whg = (const float*)d_in[8];
  const float* bg  = (const float*)d_in[9];
  const float* Wio = (const float*)d_in[10];
  const float* Who = (const float*)d_in[11];
  const float* bo  = (const float*)d_in[12];
  float* out = (float*)d_out;

  uint32_t* hbuf = (uint32_t*)d_ws;
  uint32_t* cnts = (uint32_t*)((char*)d_ws + 2u * 262144u * sizeof(__bf16));

  // zero h ping-pong + 8 barrier counters (ws re-poisoned before every launch)
  hipMemsetAsync(d_ws, 0, 2u * 262144u * sizeof(__bf16) + 8u * 1024u, stream);

  lstm_persist<<<dim3(256), dim3(512), 0, stream>>>(
      xp, Wii, Whi, bi, Wif, Whf, bf_, Wig, Whg, bg, Wio, Who, bo,
      out, hbuf, cnts);
}